// Round 2
// baseline (1101.983 us; speedup 1.0000x reference)
//
#include <hip/hip_runtime.h>
#include <hip/hip_bf16.h>
#include <stdint.h>

typedef __bf16 bf16;
typedef __bf16 bf16x8 __attribute__((ext_vector_type(8)));
typedef __bf16 bf16x4 __attribute__((ext_vector_type(4)));
typedef float f32x4 __attribute__((ext_vector_type(4)));

#define B_ 2
#define L_ 2048
#define E_ 2048
#define H_ 16
#define HKV_ 2
#define G_ 8
#define D_ 128
#define SPAST_ 2048
#define S_ 4096
#define EKV_ 256

#define MFMA16(a, b, c) __builtin_amdgcn_mfma_f32_16x16x32_bf16(a, b, c, 0, 0, 0)

__device__ __forceinline__ void gload16(const bf16* g, bf16* l) {
  __builtin_amdgcn_global_load_lds(
      (__attribute__((address_space(1))) void*)g,
      (__attribute__((address_space(3))) void*)l, 16, 0, 0);
}

// ---------------- f32 -> bf16 conversion ----------------
__global__ void cvt_kernel(const float* __restrict__ src, bf16* __restrict__ dst, int n) {
  int i = (blockIdx.x * 256 + threadIdx.x) * 4;
  if (i >= n) return;
  float4 v = *(const float4*)(src + i);
  bf16x4 o;
  o[0] = (bf16)v.x; o[1] = (bf16)v.y; o[2] = (bf16)v.z; o[3] = (bf16)v.w;
  *(bf16x4*)(dst + i) = o;
}

// ---------------- trig table ----------------
__global__ void trig_kernel(const int* __restrict__ offp, float2* __restrict__ trig) {
  int l = blockIdx.x, j = threadIdx.x;  // 64 threads
  float inv = exp2f(-(float)j * (13.287712379549449f / 64.0f));  // log2(10000)
  float ang = (float)(*offp + l) * inv;
  trig[l * 64 + j] = make_float2(cosf(ang), sinf(ang));
}

// ---------------- NT GEMM: C(M,N) = A(M,K) @ Bw(N,K)^T + bias ----------------
template <int OUTF32>
__global__ __launch_bounds__(256) void gemm_nt(const bf16* __restrict__ A,
                                               const bf16* __restrict__ Bw,
                                               const float* __restrict__ bias,
                                               void* __restrict__ Cout,
                                               int M, int N, int K) {
  __shared__ bf16 As[128 * 64];
  __shared__ bf16 Bs[128 * 64];
  const int tid = threadIdx.x;
  const int wid = tid >> 6, lane = tid & 63;
  const int ln15 = lane & 15, lq = lane >> 4;
  const int row0 = blockIdx.x * 128, col0 = blockIdx.y * 128;
  const int wr = wid >> 1, wc = wid & 1;
  f32x4 acc[4][4] = {};
  char* AsB = (char*)As;
  char* BsB = (char*)Bs;
  for (int k0 = 0; k0 < K; k0 += 64) {
#pragma unroll
    for (int j = 0; j < 4; j++) {
      int cid = j * 256 + tid;
      int r = cid >> 3, c = cid & 7;
      int csw = (c ^ (r & 7)) << 3;
      gload16(A + (size_t)(row0 + r) * K + k0 + csw, (bf16*)(AsB + (j * 256 + wid * 64) * 16));
      gload16(Bw + (size_t)(col0 + r) * K + k0 + csw, (bf16*)(BsB + (j * 256 + wid * 64) * 16));
    }
    __syncthreads();
    bf16x8 af[4][2], bfm[4][2];
#pragma unroll
    for (int m = 0; m < 4; m++) {
#pragma unroll
      for (int kk = 0; kk < 2; kk++) {
        int Ra = wr * 64 + m * 16 + ln15;
        int Rb = wc * 64 + m * 16 + ln15;
        int c = (kk << 2) + lq;
        af[m][kk] = *(const bf16x8*)(AsB + Ra * 128 + ((c ^ (Ra & 7)) << 4));
        bfm[m][kk] = *(const bf16x8*)(BsB + Rb * 128 + ((c ^ (Rb & 7)) << 4));
      }
    }
#pragma unroll
    for (int m = 0; m < 4; m++)
#pragma unroll
      for (int n = 0; n < 4; n++)
#pragma unroll
        for (int kk = 0; kk < 2; kk++)
          acc[m][n] = MFMA16(af[m][kk], bfm[n][kk], acc[m][n]);
    __syncthreads();
  }
#pragma unroll
  for (int m = 0; m < 4; m++) {
    int gr0 = row0 + wr * 64 + m * 16 + 4 * lq;
#pragma unroll
    for (int n = 0; n < 4; n++) {
      int gc = col0 + wc * 64 + n * 16 + ln15;
      float bv = bias ? bias[gc] : 0.0f;
#pragma unroll
      for (int reg = 0; reg < 4; reg++) {
        float v = acc[m][n][reg] + bv;
        size_t idx = (size_t)(gr0 + reg) * N + gc;
        if (OUTF32)
          ((float*)Cout)[idx] = v;
        else
          ((bf16*)Cout)[idx] = (bf16)v;
      }
    }
  }
}

// ---------------- RoPE on Q, scatter to (B,H,L,D), fold softmax scale*log2e ----------------
__global__ void rope_q_kernel(const bf16* __restrict__ q_lin, const float2* __restrict__ trig,
                              bf16* __restrict__ qbuf) {
  int bl = blockIdx.x;
  int b = bl >> 11, l = bl & 2047;  // L=2048
  const float QS = 0.08838834764831845f * 1.4426950408889634f;  // 1/sqrt(128) * log2(e)
  for (int i = threadIdx.x; i < H_ * 64; i += 256) {
    int h = i >> 6, j = i & 63;
    float2 cs = trig[l * 64 + j];
    float x1 = (float)q_lin[(size_t)bl * E_ + h * D_ + j];
    float x2 = (float)q_lin[(size_t)bl * E_ + h * D_ + 64 + j];
    size_t o = ((size_t)(b * H_ + h) * L_ + l) * D_ + j;
    qbuf[o] = (bf16)((x1 * cs.x - x2 * cs.y) * QS);
    qbuf[o + 64] = (bf16)((x2 * cs.x + x1 * cs.y) * QS);
  }
}

// ---------------- build k_all (B,HKV,S,D) ----------------
__global__ void build_k_kernel(const float* __restrict__ k_cache, const bf16* __restrict__ k_lin,
                               const float2* __restrict__ trig, bf16* __restrict__ k_all) {
  int d = threadIdx.x;  // 128
  int s = blockIdx.x;
  int bz = blockIdx.y;  // b*HKV + hkv
  size_t oidx = ((size_t)bz * S_ + s) * D_ + d;
  if (s < SPAST_) {
    k_all[oidx] = (bf16)k_cache[((size_t)bz * SPAST_ + s) * D_ + d];
  } else {
    int l = s - SPAST_;
    int b = bz >> 1, kh = bz & 1;
    int j = d & 63;
    float2 cs = trig[l * 64 + j];
    size_t base = (size_t)(b * L_ + l) * EKV_ + kh * D_;
    float x1 = (float)k_lin[base + j];
    float x2 = (float)k_lin[base + 64 + j];
    float v = (d < 64) ? (x1 * cs.x - x2 * cs.y) : (x2 * cs.x + x1 * cs.y);
    k_all[oidx] = (bf16)v;
  }
}

// ---------------- build transposed V: vtall (B,HKV,D,S) ----------------
__global__ void build_vt_kernel(const float* __restrict__ v_cache, const bf16* __restrict__ v_lin,
                                bf16* __restrict__ vtall) {
  __shared__ float tile[64][65];
  int s0 = blockIdx.x * 64;
  int d0 = blockIdx.y * 64;
  int bz = blockIdx.z;
  int b = bz >> 1, kh = bz & 1;
  for (int i = threadIdx.x; i < 4096; i += 256) {
    int ss = i >> 6, dd = i & 63;
    int s = s0 + ss;
    float v;
    if (s < SPAST_)
      v = v_cache[((size_t)bz * SPAST_ + s) * D_ + d0 + dd];
    else
      v = (float)v_lin[(size_t)(b * L_ + (s - SPAST_)) * EKV_ + kh * D_ + d0 + dd];
    tile[ss][dd] = v;
  }
  __syncthreads();
  for (int i = threadIdx.x; i < 4096; i += 256) {
    int dd = i >> 6, ss = i & 63;
    vtall[((size_t)bz * D_ + d0 + dd) * S_ + s0 + ss] = (bf16)tile[ss][dd];
  }
}

// ---------------- flash attention (barrier-free, direct L2 K/V reads) ----------------
// grid (L/128, B*H); 4 waves, 32 query rows each; 64-key chunks.
// K/V are L2-resident (2MB per (b,hkv)) -> no LDS staging (guide mistake #7).
// P bounced through per-wave XOR-swizzled LDS (G4 fix).
__global__ __launch_bounds__(256) void attn_kernel(const bf16* __restrict__ qbuf,
                                                   const bf16* __restrict__ k_all,
                                                   const bf16* __restrict__ vtall,
                                                   bf16* __restrict__ attnout) {
  __shared__ bf16 Ps[4 * 2 * 1024];  // per wave: 2 subtiles x 16 rows x 128B
  const int tid = threadIdx.x;
  const int wid = tid >> 6, lane = tid & 63;
  const int ln15 = lane & 15, lq = lane >> 4;
  const int q0 = blockIdx.x * 128;
  const int bh = blockIdx.y;
  const int b = bh / H_, h = bh % H_;
  const int hkv = h / G_;
  const bf16* kb = k_all + (size_t)(b * HKV_ + hkv) * S_ * D_;
  const bf16* vb = vtall + (size_t)(b * HKV_ + hkv) * D_ * S_;
  char* PsB = (char*)Ps + wid * 4096;
  // Q fragments: A row = lane&15, k = 8*(lane>>4)+i
  bf16x8 qf[2][4];
#pragma unroll
  for (int qs = 0; qs < 2; qs++) {
    int q = q0 + wid * 32 + qs * 16 + ln15;
    const bf16* qp = qbuf + ((size_t)(b * H_ + h) * L_ + q) * D_ + lq * 8;
#pragma unroll
    for (int kk = 0; kk < 4; kk++) qf[qs][kk] = *(const bf16x8*)(qp + kk * 32);
  }
  f32x4 acc[2][8] = {};
  float mrun[2][4], lrun[2][4];
#pragma unroll
  for (int qs = 0; qs < 2; qs++)
#pragma unroll
    for (int r = 0; r < 4; r++) { mrun[qs][r] = -3e38f; lrun[qs][r] = 0.f; }
  // per-wave causal bound: this wave's rows end at q0 + wid*32 + 31
  int smax = q0 + wid * 32 + 32 + SPAST_;
  if (smax > S_) smax = S_;
  const int nchunk = (smax + 63) >> 6;
  const bf16* kbl = kb + ln15 * D_ + lq * 8;                    // row ln15, d-chunk base
  const bf16* vbl = vb + (size_t)ln15 * S_ + lq * 8;            // d-row ln15, key base
  for (int sc = 0; sc < nchunk; ++sc) {
    int s0 = sc << 6;
    // ---- QK^T: scores[qs][kt], D layout col=key(ln15), row=q(4*lq+reg)
    f32x4 sc4[2][4];
#pragma unroll
    for (int kt = 0; kt < 4; kt++) {
      bf16x8 kf[4];
#pragma unroll
      for (int kk = 0; kk < 4; kk++)
        kf[kk] = *(const bf16x8*)(kbl + (size_t)(s0 + kt * 16) * D_ + kk * 32);
#pragma unroll
      for (int qs = 0; qs < 2; qs++) {
        f32x4 a = {};
#pragma unroll
        for (int kk = 0; kk < 4; kk++) a = MFMA16(qf[qs][kk], kf[kk], a);
        sc4[qs][kt] = a;
      }
    }
    // ---- mask + online softmax + P write (per subtile)
#pragma unroll
    for (int qs = 0; qs < 2; qs++) {
      int qg = q0 + wid * 32 + qs * 16 + 4 * lq;
#pragma unroll
      for (int kt = 0; kt < 4; kt++) {
        int key = s0 + kt * 16 + ln15;
#pragma unroll
        for (int reg = 0; reg < 4; reg++)
          if (key > qg + reg + SPAST_) sc4[qs][kt][reg] = -1e30f;
      }
      float fac[4];
#pragma unroll
      for (int reg = 0; reg < 4; reg++) {
        float mx = fmaxf(fmaxf(sc4[qs][0][reg], sc4[qs][1][reg]),
                         fmaxf(sc4[qs][2][reg], sc4[qs][3][reg]));
#pragma unroll
        for (int off = 1; off < 16; off <<= 1) mx = fmaxf(mx, __shfl_xor(mx, off));
        float mnew = fmaxf(mrun[qs][reg], mx);
        fac[reg] = exp2f(mrun[qs][reg] - mnew);
        mrun[qs][reg] = mnew;
      }
      float rs[4] = {0.f, 0.f, 0.f, 0.f};
#pragma unroll
      for (int kt = 0; kt < 4; kt++)
#pragma unroll
        for (int reg = 0; reg < 4; reg++) {
          float p = exp2f(sc4[qs][kt][reg] - mrun[qs][reg]);
          sc4[qs][kt][reg] = p;
          rs[reg] += p;
        }
#pragma unroll
      for (int reg = 0; reg < 4; reg++) {
#pragma unroll
        for (int off = 1; off < 16; off <<= 1) rs[reg] += __shfl_xor(rs[reg], off);
        lrun[qs][reg] = lrun[qs][reg] * fac[reg] + rs[reg];
      }
#pragma unroll
      for (int dt = 0; dt < 8; dt++)
#pragma unroll
        for (int reg = 0; reg < 4; reg++) acc[qs][dt][reg] *= fac[reg];
      // P -> LDS, XOR-swizzled 128B rows: byte = row*128 + (col ^ ((row&7)<<4))
      char* pp = PsB + qs * 2048;
#pragma unroll
      for (int kt = 0; kt < 4; kt++)
#pragma unroll
        for (int reg = 0; reg < 4; reg++) {
          int row = 4 * lq + reg;
          int col = (kt * 16 + ln15) * 2;
          *(bf16*)(pp + row * 128 + (col ^ ((row & 7) << 4))) = (bf16)sc4[qs][kt][reg];
        }
    }
    // ---- P fragments (A operand): row=ln15(q), keys 8*lq..+7 within 32-key group kc
    bf16x8 pa[2][2];
#pragma unroll
    for (int qs = 0; qs < 2; qs++)
#pragma unroll
      for (int kc = 0; kc < 2; kc++)
        pa[qs][kc] = *(const bf16x8*)(PsB + qs * 2048 + ln15 * 128 +
                                      ((kc * 64 + lq * 16) ^ ((ln15 & 7) << 4)));
    // ---- PV: V fragment shared across both subtiles
#pragma unroll
    for (int dt = 0; dt < 8; dt++) {
#pragma unroll
      for (int kc = 0; kc < 2; kc++) {
        bf16x8 vf = *(const bf16x8*)(vbl + (size_t)(dt * 16) * S_ + s0 + kc * 32);
        acc[0][dt] = MFMA16(pa[0][kc], vf, acc[0][dt]);
        acc[1][dt] = MFMA16(pa[1][kc], vf, acc[1][dt]);
      }
    }
  }
  // ---- epilogue: attnout (B, L, H*D)
#pragma unroll
  for (int qs = 0; qs < 2; qs++) {
    int qg = q0 + wid * 32 + qs * 16 + 4 * lq;
#pragma unroll
    for (int reg = 0; reg < 4; reg++) {
      float inv = 1.0f / lrun[qs][reg];
      size_t base = ((size_t)(b * L_ + qg + reg) * H_ + h) * D_;
#pragma unroll
      for (int dt = 0; dt < 8; dt++)
        attnout[base + dt * 16 + ln15] = (bf16)(acc[qs][dt][reg] * inv);
    }
  }
}

extern "C" void kernel_launch(void* const* d_in, const int* in_sizes, int n_in,
                              void* d_out, int out_size, void* d_ws, size_t ws_size,
                              hipStream_t stream) {
  const float* x = (const float*)d_in[0];
  const float* wq = (const float*)d_in[1];
  const float* wk = (const float*)d_in[2];
  const float* wv = (const float*)d_in[3];
  const float* wo = (const float*)d_in[4];
  const float* bq = (const float*)d_in[5];
  const float* bk = (const float*)d_in[6];
  const float* bv = (const float*)d_in[7];
  const float* k_cache = (const float*)d_in[8];
  const float* v_cache = (const float*)d_in[9];
  const int* offp = (const int*)d_in[10];

  char* w = (char*)d_ws;
  size_t off = 0;
  auto alloc = [&](size_t bytes) -> char* {
    char* p = w + off;
    off += (bytes + 255) & ~(size_t)255;
    return p;
  };
  const size_t nBLE = (size_t)B_ * L_ * E_;
  const size_t nBLKV = (size_t)B_ * L_ * EKV_;
  const size_t nKV = (size_t)B_ * HKV_ * S_ * D_;
  bf16* xb = (bf16*)alloc(nBLE * 2);
  bf16* wqb = (bf16*)alloc((size_t)E_ * E_ * 2);
  bf16* wkb = (bf16*)alloc((size_t)EKV_ * E_ * 2);
  bf16* wvb = (bf16*)alloc((size_t)EKV_ * E_ * 2);
  bf16* wob = (bf16*)alloc((size_t)E_ * E_ * 2);
  bf16* q_lin = (bf16*)alloc(nBLE * 2);
  bf16* k_lin = (bf16*)alloc(nBLKV * 2);
  bf16* v_lin = (bf16*)alloc(nBLKV * 2);
  bf16* qbuf = (bf16*)alloc(nBLE * 2);
  bf16* k_all = (bf16*)alloc(nKV * 2);
  bf16* vtall = (bf16*)alloc(nKV * 2);
  bf16* attnout = (bf16*)alloc(nBLE * 2);
  float2* trig = (float2*)alloc((size_t)L_ * 64 * sizeof(float2));

  cvt_kernel<<<(int)(nBLE / 1024), 256, 0, stream>>>(x, xb, (int)nBLE);
  cvt_kernel<<<(int)((size_t)E_ * E_ / 1024), 256, 0, stream>>>(wq, wqb, E_ * E_);
  cvt_kernel<<<(int)((size_t)EKV_ * E_ / 1024), 256, 0, stream>>>(wk, wkb, EKV_ * E_);
  cvt_kernel<<<(int)((size_t)EKV_ * E_ / 1024), 256, 0, stream>>>(wv, wvb, EKV_ * E_);
  cvt_kernel<<<(int)((size_t)E_ * E_ / 1024), 256, 0, stream>>>(wo, wob, E_ * E_);
  trig_kernel<<<L_, 64, 0, stream>>>(offp, trig);

  const int M = B_ * L_;  // 4096
  gemm_nt<0><<<dim3(M / 128, E_ / 128), 256, 0, stream>>>(xb, wqb, bq, q_lin, M, E_, E_);
  gemm_nt<0><<<dim3(M / 128, EKV_ / 128), 256, 0, stream>>>(xb, wkb, bk, k_lin, M, EKV_, E_);
  gemm_nt<0><<<dim3(M / 128, EKV_ / 128), 256, 0, stream>>>(xb, wvb, bv, v_lin, M, EKV_, E_);
  rope_q_kernel<<<B_ * L_, 256, 0, stream>>>(q_lin, trig, qbuf);
  build_k_kernel<<<dim3(S_, B_ * HKV_), 128, 0, stream>>>(k_cache, k_lin, trig, k_all);
  build_vt_kernel<<<dim3(S_ / 64, D_ / 64, B_ * HKV_), 256, 0, stream>>>(v_cache, v_lin, vtall);
  attn_kernel<<<dim3(L_ / 128, B_ * H_), 256, 0, stream>>>(qbuf, k_all, vtall, attnout);
  gemm_nt<1><<<dim3(M / 128, E_ / 128), 256, 0, stream>>>(attnout, wob, nullptr, d_out, M, E_, E_);
}

// Round 3
// 629.487 us; speedup vs baseline: 1.7506x; 1.7506x over previous
//
#include <hip/hip_runtime.h>
#include <hip/hip_bf16.h>
#include <stdint.h>

typedef __bf16 bf16;
typedef __bf16 bf16x8 __attribute__((ext_vector_type(8)));
typedef __bf16 bf16x4 __attribute__((ext_vector_type(4)));
typedef float f32x4 __attribute__((ext_vector_type(4)));

#define B_ 2
#define L_ 2048
#define E_ 2048
#define H_ 16
#define HKV_ 2
#define G_ 8
#define D_ 128
#define SPAST_ 2048
#define S_ 4096
#define EKV_ 256

#define MFMA16(a, b, c) __builtin_amdgcn_mfma_f32_16x16x32_bf16(a, b, c, 0, 0, 0)

__device__ __forceinline__ void gload16(const bf16* g, bf16* l) {
  __builtin_amdgcn_global_load_lds(
      (__attribute__((address_space(1))) void*)g,
      (__attribute__((address_space(3))) void*)l, 16, 0, 0);
}

// ---------------- f32 -> bf16 conversion ----------------
__global__ void cvt_kernel(const float* __restrict__ src, bf16* __restrict__ dst, int n) {
  int i = (blockIdx.x * 256 + threadIdx.x) * 4;
  if (i >= n) return;
  float4 v = *(const float4*)(src + i);
  bf16x4 o;
  o[0] = (bf16)v.x; o[1] = (bf16)v.y; o[2] = (bf16)v.z; o[3] = (bf16)v.w;
  *(bf16x4*)(dst + i) = o;
}

// ---------------- trig table ----------------
__global__ void trig_kernel(const int* __restrict__ offp, float2* __restrict__ trig) {
  int l = blockIdx.x, j = threadIdx.x;  // 64 threads
  float inv = exp2f(-(float)j * (13.287712379549449f / 64.0f));  // log2(10000)
  float ang = (float)(*offp + l) * inv;
  trig[l * 64 + j] = make_float2(cosf(ang), sinf(ang));
}

// ---------------- NT GEMM: C(M,N) = A(M,K) @ Bw(N,K)^T + bias ----------------
template <int OUTF32>
__global__ __launch_bounds__(256) void gemm_nt(const bf16* __restrict__ A,
                                               const bf16* __restrict__ Bw,
                                               const float* __restrict__ bias,
                                               void* __restrict__ Cout,
                                               int M, int N, int K) {
  __shared__ bf16 As[128 * 64];
  __shared__ bf16 Bs[128 * 64];
  const int tid = threadIdx.x;
  const int wid = tid >> 6, lane = tid & 63;
  const int ln15 = lane & 15, lq = lane >> 4;
  const int row0 = blockIdx.x * 128, col0 = blockIdx.y * 128;
  const int wr = wid >> 1, wc = wid & 1;
  f32x4 acc[4][4] = {};
  char* AsB = (char*)As;
  char* BsB = (char*)Bs;
  for (int k0 = 0; k0 < K; k0 += 64) {
#pragma unroll
    for (int j = 0; j < 4; j++) {
      int cid = j * 256 + tid;
      int r = cid >> 3, c = cid & 7;
      int csw = (c ^ (r & 7)) << 3;
      gload16(A + (size_t)(row0 + r) * K + k0 + csw, (bf16*)(AsB + (j * 256 + wid * 64) * 16));
      gload16(Bw + (size_t)(col0 + r) * K + k0 + csw, (bf16*)(BsB + (j * 256 + wid * 64) * 16));
    }
    __syncthreads();
    bf16x8 af[4][2], bfm[4][2];
#pragma unroll
    for (int m = 0; m < 4; m++) {
#pragma unroll
      for (int kk = 0; kk < 2; kk++) {
        int Ra = wr * 64 + m * 16 + ln15;
        int Rb = wc * 64 + m * 16 + ln15;
        int c = (kk << 2) + lq;
        af[m][kk] = *(const bf16x8*)(AsB + Ra * 128 + ((c ^ (Ra & 7)) << 4));
        bfm[m][kk] = *(const bf16x8*)(BsB + Rb * 128 + ((c ^ (Rb & 7)) << 4));
      }
    }
#pragma unroll
    for (int m = 0; m < 4; m++)
#pragma unroll
      for (int n = 0; n < 4; n++)
#pragma unroll
        for (int kk = 0; kk < 2; kk++)
          acc[m][n] = MFMA16(af[m][kk], bfm[n][kk], acc[m][n]);
    __syncthreads();
  }
#pragma unroll
  for (int m = 0; m < 4; m++) {
    int gr0 = row0 + wr * 64 + m * 16 + 4 * lq;
#pragma unroll
    for (int n = 0; n < 4; n++) {
      int gc = col0 + wc * 64 + n * 16 + ln15;
      float bv = bias ? bias[gc] : 0.0f;
#pragma unroll
      for (int reg = 0; reg < 4; reg++) {
        float v = acc[m][n][reg] + bv;
        size_t idx = (size_t)(gr0 + reg) * N + gc;
        if (OUTF32)
          ((float*)Cout)[idx] = v;
        else
          ((bf16*)Cout)[idx] = (bf16)v;
      }
    }
  }
}

// ---------------- RoPE on Q, scatter to (B,H,L,D), fold softmax scale*log2e ----------------
__global__ void rope_q_kernel(const bf16* __restrict__ q_lin, const float2* __restrict__ trig,
                              bf16* __restrict__ qbuf) {
  int bl = blockIdx.x;
  int b = bl >> 11, l = bl & 2047;  // L=2048
  const float QS = 0.08838834764831845f * 1.4426950408889634f;  // 1/sqrt(128) * log2(e)
  for (int i = threadIdx.x; i < H_ * 64; i += 256) {
    int h = i >> 6, j = i & 63;
    float2 cs = trig[l * 64 + j];
    float x1 = (float)q_lin[(size_t)bl * E_ + h * D_ + j];
    float x2 = (float)q_lin[(size_t)bl * E_ + h * D_ + 64 + j];
    size_t o = ((size_t)(b * H_ + h) * L_ + l) * D_ + j;
    qbuf[o] = (bf16)((x1 * cs.x - x2 * cs.y) * QS);
    qbuf[o + 64] = (bf16)((x2 * cs.x + x1 * cs.y) * QS);
  }
}

// ---------------- build k_all (B,HKV,S,D) ----------------
__global__ void build_k_kernel(const float* __restrict__ k_cache, const bf16* __restrict__ k_lin,
                               const float2* __restrict__ trig, bf16* __restrict__ k_all) {
  int d = threadIdx.x;  // 128
  int s = blockIdx.x;
  int bz = blockIdx.y;  // b*HKV + hkv
  size_t oidx = ((size_t)bz * S_ + s) * D_ + d;
  if (s < SPAST_) {
    k_all[oidx] = (bf16)k_cache[((size_t)bz * SPAST_ + s) * D_ + d];
  } else {
    int l = s - SPAST_;
    int b = bz >> 1, kh = bz & 1;
    int j = d & 63;
    float2 cs = trig[l * 64 + j];
    size_t base = (size_t)(b * L_ + l) * EKV_ + kh * D_;
    float x1 = (float)k_lin[base + j];
    float x2 = (float)k_lin[base + 64 + j];
    float v = (d < 64) ? (x1 * cs.x - x2 * cs.y) : (x2 * cs.x + x1 * cs.y);
    k_all[oidx] = (bf16)v;
  }
}

// ---------------- build transposed V: vtall (B,HKV,D,S) ----------------
__global__ void build_vt_kernel(const float* __restrict__ v_cache, const bf16* __restrict__ v_lin,
                                bf16* __restrict__ vtall) {
  __shared__ float tile[64][65];
  int s0 = blockIdx.x * 64;
  int d0 = blockIdx.y * 64;
  int bz = blockIdx.z;
  int b = bz >> 1, kh = bz & 1;
  for (int i = threadIdx.x; i < 4096; i += 256) {
    int ss = i >> 6, dd = i & 63;
    int s = s0 + ss;
    float v;
    if (s < SPAST_)
      v = v_cache[((size_t)bz * SPAST_ + s) * D_ + d0 + dd];
    else
      v = (float)v_lin[(size_t)(b * L_ + (s - SPAST_)) * EKV_ + kh * D_ + d0 + dd];
    tile[ss][dd] = v;
  }
  __syncthreads();
  for (int i = threadIdx.x; i < 4096; i += 256) {
    int dd = i >> 6, ss = i & 63;
    vtall[((size_t)bz * D_ + d0 + dd) * S_ + s0 + ss] = (bf16)tile[ss][dd];
  }
}

// ---------------- flash attention: 2-phase pipelined LDS staging ----------------
// grid (L/128, B*H); 4 waves x 32 q-rows; 64-key chunks, double-buffered K/V in LDS.
// T3-minimum recipe: STAGE(next) issued before compute, one drain+barrier per chunk.
__global__ __launch_bounds__(256) void attn_kernel(const bf16* __restrict__ qbuf,
                                                   const bf16* __restrict__ k_all,
                                                   const bf16* __restrict__ vtall,
                                                   bf16* __restrict__ attnout) {
  __shared__ bf16 Ks[2 * 64 * 128];   // 2 x 16KB, [key][d], linear+src-swizzled
  __shared__ bf16 Vs[2 * 128 * 64];   // 2 x 16KB, [d][key]
  __shared__ bf16 Ps[4 * 1024];       // 2KB per wave, reused across 2 q-subtiles
  const int tid = threadIdx.x;
  const int wid = tid >> 6, lane = tid & 63;
  const int ln15 = lane & 15, lq = lane >> 4;
  const int q0 = blockIdx.x * 128;
  const int bh = blockIdx.y;
  const int b = bh / H_, h = bh % H_;
  const int hkv = h / G_;
  const bf16* kb = k_all + (size_t)(b * HKV_ + hkv) * S_ * D_;
  const bf16* vb = vtall + (size_t)(b * HKV_ + hkv) * D_ * S_;
  char* PsB = (char*)Ps + wid * 2048;
  // Q fragments: A row = lane&15, k = 8*(lane>>4)+i
  bf16x8 qf[2][4];
#pragma unroll
  for (int qs = 0; qs < 2; qs++) {
    int q = q0 + wid * 32 + qs * 16 + ln15;
    const bf16* qp = qbuf + ((size_t)(b * H_ + h) * L_ + q) * D_ + lq * 8;
#pragma unroll
    for (int kk = 0; kk < 4; kk++) qf[qs][kk] = *(const bf16x8*)(qp + kk * 32);
  }
  f32x4 acc[2][8] = {};
  float mrun[2][4], lrun[2][4];
#pragma unroll
  for (int qs = 0; qs < 2; qs++)
#pragma unroll
    for (int r = 0; r < 4; r++) { mrun[qs][r] = -3e38f; lrun[qs][r] = 0.f; }

  auto STAGE = [&](int buf, int s0) {
    char* kd = (char*)Ks + buf * 16384;
    char* vd = (char*)Vs + buf * 16384;
#pragma unroll
    for (int j = 0; j < 4; j++) {
      int cid = j * 256 + tid;
      {  // K: 64 rows x 16 chunks of 16B
        int r = cid >> 4, c = cid & 15;
        gload16(kb + (size_t)(s0 + r) * D_ + ((c ^ (r & 7)) << 3),
                (bf16*)(kd + (j * 256 + wid * 64) * 16));
      }
      {  // V^T: 128 rows x 8 chunks of 16B
        int r = cid >> 3, c = cid & 7;
        gload16(vb + (size_t)r * S_ + s0 + ((c ^ (r & 7)) << 3),
                (bf16*)(vd + (j * 256 + wid * 64) * 16));
      }
    }
  };

  // block-uniform chunk count (barriers require it); per-wave compute guard
  const int smax_blk = q0 + 128 + SPAST_;  // <= S_ always
  const int nchunk = smax_blk >> 6;
  const int smax_w = q0 + wid * 32 + 32 + SPAST_;

  STAGE(0, 0);
  __syncthreads();
  int cur = 0;
  for (int sc = 0; sc < nchunk; ++sc) {
    int s0 = sc << 6;
    if (sc + 1 < nchunk) STAGE(cur ^ 1, s0 + 64);  // prefetch next chunk (in flight across compute)
    if (s0 < smax_w) {
      char* kcur = (char*)Ks + cur * 16384;
      char* vcur = (char*)Vs + cur * 16384;
      // ---- QK^T: sc4[qs][kt], D layout col=key(ln15), row=q(4*lq+reg)
      f32x4 sc4[2][4];
#pragma unroll
      for (int kt = 0; kt < 4; kt++) {
        bf16x8 kf[4];
        int R = kt * 16 + ln15;
#pragma unroll
        for (int kk = 0; kk < 4; kk++) {
          int c = (kk << 2) + lq;
          kf[kk] = *(const bf16x8*)(kcur + R * 256 + ((c ^ (R & 7)) << 4));
        }
#pragma unroll
        for (int qs = 0; qs < 2; qs++) {
          f32x4 a = {};
#pragma unroll
          for (int kk = 0; kk < 4; kk++) a = MFMA16(qf[qs][kk], kf[kk], a);
          sc4[qs][kt] = a;
        }
      }
      // ---- per subtile: mask, online softmax (T13 defer-max), P bounce, pa read
      bf16x8 pa[2][2];
#pragma unroll
      for (int qs = 0; qs < 2; qs++) {
        int qg = q0 + wid * 32 + qs * 16 + 4 * lq;
#pragma unroll
        for (int kt = 0; kt < 4; kt++) {
          int key = s0 + kt * 16 + ln15;
#pragma unroll
          for (int reg = 0; reg < 4; reg++)
            if (key > qg + reg + SPAST_) sc4[qs][kt][reg] = -1e30f;
        }
        float mx[4];
#pragma unroll
        for (int reg = 0; reg < 4; reg++) {
          float m = fmaxf(fmaxf(sc4[qs][0][reg], sc4[qs][1][reg]),
                          fmaxf(sc4[qs][2][reg], sc4[qs][3][reg]));
#pragma unroll
          for (int off = 1; off < 16; off <<= 1) m = fmaxf(m, __shfl_xor(m, off));
          mx[reg] = m;
        }
        // T13: only rescale when tile max exceeds running max by >8 (P bounded by 2^8)
        float g = -3e38f;
#pragma unroll
        for (int reg = 0; reg < 4; reg++) g = fmaxf(g, mx[reg] - mrun[qs][reg]);
        if (__any(g > 8.0f)) {
#pragma unroll
          for (int reg = 0; reg < 4; reg++) {
            float mnew = fmaxf(mrun[qs][reg], mx[reg]);
            float fac = exp2f(mrun[qs][reg] - mnew);
            mrun[qs][reg] = mnew;
            lrun[qs][reg] *= fac;
#pragma unroll
            for (int dt = 0; dt < 8; dt++) acc[qs][dt][reg] *= fac;
          }
        }
        float rs[4] = {0.f, 0.f, 0.f, 0.f};
#pragma unroll
        for (int kt = 0; kt < 4; kt++)
#pragma unroll
          for (int reg = 0; reg < 4; reg++) {
            float p = exp2f(sc4[qs][kt][reg] - mrun[qs][reg]);
            sc4[qs][kt][reg] = p;
            rs[reg] += p;
          }
#pragma unroll
        for (int reg = 0; reg < 4; reg++) {
#pragma unroll
          for (int off = 1; off < 16; off <<= 1) rs[reg] += __shfl_xor(rs[reg], off);
          lrun[qs][reg] += rs[reg];
        }
        // P -> LDS (swizzled 128B rows), then read A-fragments back
#pragma unroll
        for (int kt = 0; kt < 4; kt++)
#pragma unroll
          for (int reg = 0; reg < 4; reg++) {
            int row = 4 * lq + reg;
            int col = (kt * 16 + ln15) * 2;
            *(bf16*)(PsB + row * 128 + (col ^ ((row & 7) << 4))) = (bf16)sc4[qs][kt][reg];
          }
#pragma unroll
        for (int kc = 0; kc < 2; kc++)
          pa[qs][kc] = *(const bf16x8*)(PsB + ln15 * 128 +
                                        ((kc * 64 + lq * 16) ^ ((ln15 & 7) << 4)));
      }
      // ---- PV: V fragment shared across both subtiles
#pragma unroll
      for (int dt = 0; dt < 8; dt++) {
        int R = dt * 16 + ln15;
#pragma unroll
        for (int kc = 0; kc < 2; kc++) {
          int c = (kc << 2) + lq;
          bf16x8 vf = *(const bf16x8*)(vcur + R * 128 + ((c ^ (R & 7)) << 4));
          acc[0][dt] = MFMA16(pa[0][kc], vf, acc[0][dt]);
          acc[1][dt] = MFMA16(pa[1][kc], vf, acc[1][dt]);
        }
      }
    }
    __syncthreads();  // drains vmcnt (next-chunk staging complete) + wave sync
    cur ^= 1;
  }
  // ---- epilogue: attnout (B, L, H*D)
#pragma unroll
  for (int qs = 0; qs < 2; qs++) {
    int qg = q0 + wid * 32 + qs * 16 + 4 * lq;
#pragma unroll
    for (int reg = 0; reg < 4; reg++) {
      float inv = 1.0f / lrun[qs][reg];
      size_t base = ((size_t)(b * L_ + qg + reg) * H_ + h) * D_;
#pragma unroll
      for (int dt = 0; dt < 8; dt++)
        attnout[base + dt * 16 + ln15] = (bf16)(acc[qs][dt][reg] * inv);
    }
  }
}

extern "C" void kernel_launch(void* const* d_in, const int* in_sizes, int n_in,
                              void* d_out, int out_size, void* d_ws, size_t ws_size,
                              hipStream_t stream) {
  const float* x = (const float*)d_in[0];
  const float* wq = (const float*)d_in[1];
  const float* wk = (const float*)d_in[2];
  const float* wv = (const float*)d_in[3];
  const float* wo = (const float*)d_in[4];
  const float* bq = (const float*)d_in[5];
  const float* bk = (const float*)d_in[6];
  const float* bv = (const float*)d_in[7];
  const float* k_cache = (const float*)d_in[8];
  const float* v_cache = (const float*)d_in[9];
  const int* offp = (const int*)d_in[10];

  char* w = (char*)d_ws;
  size_t off = 0;
  auto alloc = [&](size_t bytes) -> char* {
    char* p = w + off;
    off += (bytes + 255) & ~(size_t)255;
    return p;
  };
  const size_t nBLE = (size_t)B_ * L_ * E_;
  const size_t nBLKV = (size_t)B_ * L_ * EKV_;
  const size_t nKV = (size_t)B_ * HKV_ * S_ * D_;
  bf16* xb = (bf16*)alloc(nBLE * 2);
  bf16* wqb = (bf16*)alloc((size_t)E_ * E_ * 2);
  bf16* wkb = (bf16*)alloc((size_t)EKV_ * E_ * 2);
  bf16* wvb = (bf16*)alloc((size_t)EKV_ * E_ * 2);
  bf16* wob = (bf16*)alloc((size_t)E_ * E_ * 2);
  bf16* q_lin = (bf16*)alloc(nBLE * 2);
  bf16* k_lin = (bf16*)alloc(nBLKV * 2);
  bf16* v_lin = (bf16*)alloc(nBLKV * 2);
  bf16* qbuf = (bf16*)alloc(nBLE * 2);
  bf16* k_all = (bf16*)alloc(nKV * 2);
  bf16* vtall = (bf16*)alloc(nKV * 2);
  bf16* attnout = (bf16*)alloc(nBLE * 2);
  float2* trig = (float2*)alloc((size_t)L_ * 64 * sizeof(float2));

  cvt_kernel<<<(int)(nBLE / 1024), 256, 0, stream>>>(x, xb, (int)nBLE);
  cvt_kernel<<<(int)((size_t)E_ * E_ / 1024), 256, 0, stream>>>(wq, wqb, E_ * E_);
  cvt_kernel<<<(int)((size_t)EKV_ * E_ / 1024), 256, 0, stream>>>(wk, wkb, EKV_ * E_);
  cvt_kernel<<<(int)((size_t)EKV_ * E_ / 1024), 256, 0, stream>>>(wv, wvb, EKV_ * E_);
  cvt_kernel<<<(int)((size_t)E_ * E_ / 1024), 256, 0, stream>>>(wo, wob, E_ * E_);
  trig_kernel<<<L_, 64, 0, stream>>>(offp, trig);

  const int M = B_ * L_;  // 4096
  gemm_nt<0><<<dim3(M / 128, E_ / 128), 256, 0, stream>>>(xb, wqb, bq, q_lin, M, E_, E_);
  gemm_nt<0><<<dim3(M / 128, EKV_ / 128), 256, 0, stream>>>(xb, wkb, bk, k_lin, M, EKV_, E_);
  gemm_nt<0><<<dim3(M / 128, EKV_ / 128), 256, 0, stream>>>(xb, wvb, bv, v_lin, M, EKV_, E_);
  rope_q_kernel<<<B_ * L_, 256, 0, stream>>>(q_lin, trig, qbuf);
  build_k_kernel<<<dim3(S_, B_ * HKV_), 128, 0, stream>>>(k_cache, k_lin, trig, k_all);
  build_vt_kernel<<<dim3(S_ / 64, D_ / 64, B_ * HKV_), 256, 0, stream>>>(v_cache, v_lin, vtall);
  attn_kernel<<<dim3(L_ / 128, B_ * H_), 256, 0, stream>>>(qbuf, k_all, vtall, attnout);
  gemm_nt<1><<<dim3(M / 128, E_ / 128), 256, 0, stream>>>(attnout, wob, nullptr, d_out, M, E_, E_);
}

// Round 4
// 394.494 us; speedup vs baseline: 2.7934x; 1.5957x over previous
//
#include <hip/hip_runtime.h>
#include <hip/hip_bf16.h>
#include <stdint.h>

typedef __bf16 bf16;
typedef __bf16 bf16x8 __attribute__((ext_vector_type(8)));
typedef __bf16 bf16x4 __attribute__((ext_vector_type(4)));
typedef float f32x4 __attribute__((ext_vector_type(4)));

#define B_ 2
#define L_ 2048
#define E_ 2048
#define H_ 16
#define HKV_ 2
#define G_ 8
#define D_ 128
#define SPAST_ 2048
#define S_ 4096
#define EKV_ 256

#define MFMA16(a, b, c) __builtin_amdgcn_mfma_f32_16x16x32_bf16(a, b, c, 0, 0, 0)

__device__ __forceinline__ void gload16(const bf16* g, bf16* l) {
  __builtin_amdgcn_global_load_lds(
      (__attribute__((address_space(1))) void*)g,
      (__attribute__((address_space(3))) void*)l, 16, 0, 0);
}

// ---------------- f32 -> bf16 conversion ----------------
__global__ void cvt_kernel(const float* __restrict__ src, bf16* __restrict__ dst, int n) {
  int i = (blockIdx.x * 256 + threadIdx.x) * 4;
  if (i >= n) return;
  float4 v = *(const float4*)(src + i);
  bf16x4 o;
  o[0] = (bf16)v.x; o[1] = (bf16)v.y; o[2] = (bf16)v.z; o[3] = (bf16)v.w;
  *(bf16x4*)(dst + i) = o;
}

// ---------------- trig table ----------------
__global__ void trig_kernel(const int* __restrict__ offp, float2* __restrict__ trig) {
  int l = blockIdx.x, j = threadIdx.x;  // 64 threads
  float inv = exp2f(-(float)j * (13.287712379549449f / 64.0f));  // log2(10000)
  float ang = (float)(*offp + l) * inv;
  trig[l * 64 + j] = make_float2(cosf(ang), sinf(ang));
}

// ---------------- NT GEMM: C(M,N) = A(M,K) @ Bw(N,K)^T + bias ----------------
template <int OUTF32>
__global__ __launch_bounds__(256) void gemm_nt(const bf16* __restrict__ A,
                                               const bf16* __restrict__ Bw,
                                               const float* __restrict__ bias,
                                               void* __restrict__ Cout,
                                               int M, int N, int K) {
  __shared__ bf16 As[128 * 64];
  __shared__ bf16 Bs[128 * 64];
  const int tid = threadIdx.x;
  const int wid = tid >> 6, lane = tid & 63;
  const int ln15 = lane & 15, lq = lane >> 4;
  const int row0 = blockIdx.x * 128, col0 = blockIdx.y * 128;
  const int wr = wid >> 1, wc = wid & 1;
  f32x4 acc[4][4] = {};
  char* AsB = (char*)As;
  char* BsB = (char*)Bs;
  for (int k0 = 0; k0 < K; k0 += 64) {
#pragma unroll
    for (int j = 0; j < 4; j++) {
      int cid = j * 256 + tid;
      int r = cid >> 3, c = cid & 7;
      int csw = (c ^ (r & 7)) << 3;
      gload16(A + (size_t)(row0 + r) * K + k0 + csw, (bf16*)(AsB + (j * 256 + wid * 64) * 16));
      gload16(Bw + (size_t)(col0 + r) * K + k0 + csw, (bf16*)(BsB + (j * 256 + wid * 64) * 16));
    }
    __syncthreads();
    bf16x8 af[4][2], bfm[4][2];
#pragma unroll
    for (int m = 0; m < 4; m++) {
#pragma unroll
      for (int kk = 0; kk < 2; kk++) {
        int Ra = wr * 64 + m * 16 + ln15;
        int Rb = wc * 64 + m * 16 + ln15;
        int c = (kk << 2) + lq;
        af[m][kk] = *(const bf16x8*)(AsB + Ra * 128 + ((c ^ (Ra & 7)) << 4));
        bfm[m][kk] = *(const bf16x8*)(BsB + Rb * 128 + ((c ^ (Rb & 7)) << 4));
      }
    }
#pragma unroll
    for (int m = 0; m < 4; m++)
#pragma unroll
      for (int n = 0; n < 4; n++)
#pragma unroll
        for (int kk = 0; kk < 2; kk++)
          acc[m][n] = MFMA16(af[m][kk], bfm[n][kk], acc[m][n]);
    __syncthreads();
  }
#pragma unroll
  for (int m = 0; m < 4; m++) {
    int gr0 = row0 + wr * 64 + m * 16 + 4 * lq;
#pragma unroll
    for (int n = 0; n < 4; n++) {
      int gc = col0 + wc * 64 + n * 16 + ln15;
      float bv = bias ? bias[gc] : 0.0f;
#pragma unroll
      for (int reg = 0; reg < 4; reg++) {
        float v = acc[m][n][reg] + bv;
        size_t idx = (size_t)(gr0 + reg) * N + gc;
        if (OUTF32)
          ((float*)Cout)[idx] = v;
        else
          ((bf16*)Cout)[idx] = (bf16)v;
      }
    }
  }
}

// ---------------- RoPE on Q, scatter to (B,H,L,D), fold softmax scale*log2e ----------------
__global__ void rope_q_kernel(const bf16* __restrict__ q_lin, const float2* __restrict__ trig,
                              bf16* __restrict__ qbuf) {
  int bl = blockIdx.x;
  int b = bl >> 11, l = bl & 2047;  // L=2048
  const float QS = 0.08838834764831845f * 1.4426950408889634f;  // 1/sqrt(128) * log2(e)
  for (int i = threadIdx.x; i < H_ * 64; i += 256) {
    int h = i >> 6, j = i & 63;
    float2 cs = trig[l * 64 + j];
    float x1 = (float)q_lin[(size_t)bl * E_ + h * D_ + j];
    float x2 = (float)q_lin[(size_t)bl * E_ + h * D_ + 64 + j];
    size_t o = ((size_t)(b * H_ + h) * L_ + l) * D_ + j;
    qbuf[o] = (bf16)((x1 * cs.x - x2 * cs.y) * QS);
    qbuf[o + 64] = (bf16)((x2 * cs.x + x1 * cs.y) * QS);
  }
}

// ---------------- build k_all (B,HKV,S,D) ----------------
__global__ void build_k_kernel(const float* __restrict__ k_cache, const bf16* __restrict__ k_lin,
                               const float2* __restrict__ trig, bf16* __restrict__ k_all) {
  int d = threadIdx.x;  // 128
  int s = blockIdx.x;
  int bz = blockIdx.y;  // b*HKV + hkv
  size_t oidx = ((size_t)bz * S_ + s) * D_ + d;
  if (s < SPAST_) {
    k_all[oidx] = (bf16)k_cache[((size_t)bz * SPAST_ + s) * D_ + d];
  } else {
    int l = s - SPAST_;
    int b = bz >> 1, kh = bz & 1;
    int j = d & 63;
    float2 cs = trig[l * 64 + j];
    size_t base = (size_t)(b * L_ + l) * EKV_ + kh * D_;
    float x1 = (float)k_lin[base + j];
    float x2 = (float)k_lin[base + 64 + j];
    float v = (d < 64) ? (x1 * cs.x - x2 * cs.y) : (x2 * cs.x + x1 * cs.y);
    k_all[oidx] = (bf16)v;
  }
}

// ---------------- build transposed V: vtall (B,HKV,D,S) ----------------
__global__ void build_vt_kernel(const float* __restrict__ v_cache, const bf16* __restrict__ v_lin,
                                bf16* __restrict__ vtall) {
  __shared__ float tile[64][65];
  int s0 = blockIdx.x * 64;
  int d0 = blockIdx.y * 64;
  int bz = blockIdx.z;
  int b = bz >> 1, kh = bz & 1;
  for (int i = threadIdx.x; i < 4096; i += 256) {
    int ss = i >> 6, dd = i & 63;
    int s = s0 + ss;
    float v;
    if (s < SPAST_)
      v = v_cache[((size_t)bz * SPAST_ + s) * D_ + d0 + dd];
    else
      v = (float)v_lin[(size_t)(b * L_ + (s - SPAST_)) * EKV_ + kh * D_ + d0 + dd];
    tile[ss][dd] = v;
  }
  __syncthreads();
  for (int i = threadIdx.x; i < 4096; i += 256) {
    int dd = i >> 6, ss = i & 63;
    vtall[((size_t)bz * D_ + d0 + dd) * S_ + s0 + ss] = (bf16)tile[ss][dd];
  }
}

// ---------------- flash attention: swapped-QK^T, 2-phase pipelined staging ----------------
// grid (16, 32); 4 waves x 32 q-rows; 64-key chunks, double-buffered K/V in LDS.
// Swapped MFMA (A=K,B=Q -> S^T): per-lane P-row => in-lane softmax (2 shfl), vector P-pack.
__global__ __launch_bounds__(256, 2) void attn_kernel(const bf16* __restrict__ qbuf,
                                                      const bf16* __restrict__ k_all,
                                                      const bf16* __restrict__ vtall,
                                                      bf16* __restrict__ attnout) {
  __shared__ bf16 Ks[2 * 64 * 128];   // 2 x 16KB, [key][d], linear+src-swizzled
  __shared__ bf16 Vs[2 * 128 * 64];   // 2 x 16KB, [d][key]
  __shared__ bf16 Ps[4 * 16 * 64];    // 2KB per wave: P^T rows q=0..15, 64 keys, swizzled
  const int tid = threadIdx.x;
  const int wid = tid >> 6, lane = tid & 63;
  const int ln15 = lane & 15, lq = lane >> 4;
  // balance remap: co-resident blocks (x,y) and (x,y+16) get q-blocks x and 15-x
  const int xq = ((blockIdx.y >> 4) & 1) ? (15 - (int)blockIdx.x) : (int)blockIdx.x;
  const int q0 = xq * 128;
  const int bh = blockIdx.y;
  const int b = bh / H_, h = bh % H_;
  const int hkv = h / G_;
  const bf16* kb = k_all + (size_t)(b * HKV_ + hkv) * S_ * D_;
  const bf16* vb = vtall + (size_t)(b * HKV_ + hkv) * D_ * S_;
  char* PsB = (char*)Ps + wid * 2048;
  const int swz = (ln15 & 7) << 4;
  // Q fragments (B-operand): col=q=ln15, k = 8*lq+i
  bf16x8 qf[2][4];
#pragma unroll
  for (int qs = 0; qs < 2; qs++) {
    int q = q0 + wid * 32 + qs * 16 + ln15;
    const bf16* qp = qbuf + ((size_t)(b * H_ + h) * L_ + q) * D_ + lq * 8;
#pragma unroll
    for (int kk = 0; kk < 4; kk++) qf[qs][kk] = *(const bf16x8*)(qp + kk * 32);
  }
  f32x4 acc[2][8] = {};
  float mr[2] = {-3e38f, -3e38f}, lr[2] = {0.f, 0.f};

  auto STAGE = [&](int buf, int s0) {
    char* kd = (char*)Ks + buf * 16384;
    char* vd = (char*)Vs + buf * 16384;
#pragma unroll
    for (int j = 0; j < 4; j++) {
      int cid = j * 256 + tid;
      {  // K: 64 rows x 16 chunks of 16B
        int r = cid >> 4, c = cid & 15;
        gload16(kb + (size_t)(s0 + r) * D_ + ((c ^ (r & 7)) << 3),
                (bf16*)(kd + (j * 256 + wid * 64) * 16));
      }
      {  // V^T: 128 rows x 8 chunks of 16B
        int r = cid >> 3, c = cid & 7;
        gload16(vb + (size_t)r * S_ + s0 + ((c ^ (r & 7)) << 3),
                (bf16*)(vd + (j * 256 + wid * 64) * 16));
      }
    }
  };

  const int nchunk = (q0 + 128 + SPAST_) >> 6;  // block-uniform
  const int smax_w = q0 + wid * 32 + 32 + SPAST_;

  STAGE(0, 0);
  __syncthreads();
  int cur = 0;
  for (int sc = 0; sc < nchunk; ++sc) {
    int s0 = sc << 6;
    if (sc + 1 < nchunk) STAGE(cur ^ 1, s0 + 64);  // prefetch next chunk
    if (s0 < smax_w) {
      char* kcur = (char*)Ks + cur * 16384;
      char* vcur = (char*)Vs + cur * 16384;
      // ---- swapped QK^T: st[qs][kt]; lane holds q=ln15, keys kt*16+4lq+reg
      f32x4 st[2][4];
      __builtin_amdgcn_s_setprio(1);
#pragma unroll
      for (int kt = 0; kt < 4; kt++) {
        bf16x8 kf[4];
        int R = kt * 16 + ln15;
#pragma unroll
        for (int kk = 0; kk < 4; kk++) {
          int c = (kk << 2) + lq;
          kf[kk] = *(const bf16x8*)(kcur + R * 256 + ((c ^ (R & 7)) << 4));
        }
#pragma unroll
        for (int qs = 0; qs < 2; qs++) {
          f32x4 a = {};
#pragma unroll
          for (int kk = 0; kk < 4; kk++) a = MFMA16(kf[kk], qf[qs][kk], a);
          st[qs][kt] = a;
        }
      }
      __builtin_amdgcn_s_setprio(0);
      // ---- per subtile: mask, in-lane online softmax, P^T pack -> LDS, pa read
      bf16x8 pa[2][2];
#pragma unroll
      for (int qs = 0; qs < 2; qs++) {
        int qabs = q0 + wid * 32 + qs * 16 + ln15;
        int kbase = s0 + 4 * lq;
#pragma unroll
        for (int kt = 0; kt < 4; kt++) {
#pragma unroll
          for (int reg = 0; reg < 4; reg++)
            if (kbase + kt * 16 + reg > qabs + SPAST_) st[qs][kt][reg] = -1e30f;
        }
        // in-lane max tree (depth 4) + 2 cross-lane shuffles
        float t0 = fmaxf(fmaxf(st[qs][0][0], st[qs][0][1]), fmaxf(st[qs][0][2], st[qs][0][3]));
        float t1 = fmaxf(fmaxf(st[qs][1][0], st[qs][1][1]), fmaxf(st[qs][1][2], st[qs][1][3]));
        float t2 = fmaxf(fmaxf(st[qs][2][0], st[qs][2][1]), fmaxf(st[qs][2][2], st[qs][2][3]));
        float t3 = fmaxf(fmaxf(st[qs][3][0], st[qs][3][1]), fmaxf(st[qs][3][2], st[qs][3][3]));
        float mt = fmaxf(fmaxf(t0, t1), fmaxf(t2, t3));
        mt = fmaxf(mt, __shfl_xor(mt, 16));
        mt = fmaxf(mt, __shfl_xor(mt, 32));
        // T13 defer-max: rescale only when tile max exceeds running max by >8
        if (__any(mt - mr[qs] > 8.0f)) {
          float mn = fmaxf(mr[qs], mt);
          float fac = exp2f(mr[qs] - mn);
          mr[qs] = mn;
          lr[qs] *= fac;
#pragma unroll
          for (int dt = 0; dt < 8; dt++)
#pragma unroll
            for (int reg = 0; reg < 4; reg++) acc[qs][dt][reg] *= fac;
        }
        float s01 = 0.f, s23 = 0.f;
#pragma unroll
        for (int kt = 0; kt < 4; kt++) {
          f32x4 p;
#pragma unroll
          for (int reg = 0; reg < 4; reg++) p[reg] = exp2f(st[qs][kt][reg] - mr[qs]);
          st[qs][kt] = p;
          s01 += (p[0] + p[1]);
          s23 += (p[2] + p[3]);
        }
        float s = s01 + s23;
        s += __shfl_xor(s, 16);
        s += __shfl_xor(s, 32);
        lr[qs] += s;
        // P^T pack -> LDS row q=ln15 (swizzled), one b64 per kt
#pragma unroll
        for (int kt = 0; kt < 4; kt++) {
          bf16x4 pk;
#pragma unroll
          for (int reg = 0; reg < 4; reg++) pk[reg] = (bf16)st[qs][kt][reg];
          *(bf16x4*)(PsB + ln15 * 128 + ((kt * 32 + lq * 8) ^ swz)) = pk;
        }
        // B-operand fragments: col=q=ln15, k = kc*32 + 8*lq + i
#pragma unroll
        for (int kc = 0; kc < 2; kc++)
          pa[qs][kc] = *(const bf16x8*)(PsB + ln15 * 128 + ((kc * 64 + lq * 16) ^ swz));
      }
      // ---- PV: O^T = V^T x P^T; vf shared across both subtiles
      __builtin_amdgcn_s_setprio(1);
#pragma unroll
      for (int dt = 0; dt < 8; dt++) {
        int R = dt * 16 + ln15;
#pragma unroll
        for (int kc = 0; kc < 2; kc++) {
          int c = (kc << 2) + lq;
          bf16x8 vf = *(const bf16x8*)(vcur + R * 128 + ((c ^ (R & 7)) << 4));
          acc[0][dt] = MFMA16(vf, pa[0][kc], acc[0][dt]);
          acc[1][dt] = MFMA16(vf, pa[1][kc], acc[1][dt]);
        }
      }
      __builtin_amdgcn_s_setprio(0);
    }
    __syncthreads();  // drains vmcnt (staging done) + wave sync
    cur ^= 1;
  }
  // ---- epilogue: lane holds O[q=ln15-based][d=dt*16+4lq+reg] -> 8B stores
#pragma unroll
  for (int qs = 0; qs < 2; qs++) {
    int q = q0 + wid * 32 + qs * 16 + ln15;
    float inv = 1.0f / lr[qs];
    size_t base = ((size_t)(b * L_ + q) * H_ + h) * D_ + 4 * lq;
#pragma unroll
    for (int dt = 0; dt < 8; dt++) {
      bf16x4 o;
#pragma unroll
      for (int reg = 0; reg < 4; reg++) o[reg] = (bf16)(acc[qs][dt][reg] * inv);
      *(bf16x4*)(attnout + base + dt * 16) = o;
    }
  }
}

extern "C" void kernel_launch(void* const* d_in, const int* in_sizes, int n_in,
                              void* d_out, int out_size, void* d_ws, size_t ws_size,
                              hipStream_t stream) {
  const float* x = (const float*)d_in[0];
  const float* wq = (const float*)d_in[1];
  const float* wk = (const float*)d_in[2];
  const float* wv = (const float*)d_in[3];
  const float* wo = (const float*)d_in[4];
  const float* bq = (const float*)d_in[5];
  const float* bk = (const float*)d_in[6];
  const float* bv = (const float*)d_in[7];
  const float* k_cache = (const float*)d_in[8];
  const float* v_cache = (const float*)d_in[9];
  const int* offp = (const int*)d_in[10];

  char* w = (char*)d_ws;
  size_t off = 0;
  auto alloc = [&](size_t bytes) -> char* {
    char* p = w + off;
    off += (bytes + 255) & ~(size_t)255;
    return p;
  };
  const size_t nBLE = (size_t)B_ * L_ * E_;
  const size_t nBLKV = (size_t)B_ * L_ * EKV_;
  const size_t nKV = (size_t)B_ * HKV_ * S_ * D_;
  bf16* xb = (bf16*)alloc(nBLE * 2);
  bf16* wqb = (bf16*)alloc((size_t)E_ * E_ * 2);
  bf16* wkb = (bf16*)alloc((size_t)EKV_ * E_ * 2);
  bf16* wvb = (bf16*)alloc((size_t)EKV_ * E_ * 2);
  bf16* wob = (bf16*)alloc((size_t)E_ * E_ * 2);
  bf16* q_lin = (bf16*)alloc(nBLE * 2);
  bf16* k_lin = (bf16*)alloc(nBLKV * 2);
  bf16* v_lin = (bf16*)alloc(nBLKV * 2);
  bf16* qbuf = (bf16*)alloc(nBLE * 2);
  bf16* k_all = (bf16*)alloc(nKV * 2);
  bf16* vtall = (bf16*)alloc(nKV * 2);
  bf16* attnout = (bf16*)alloc(nBLE * 2);
  float2* trig = (float2*)alloc((size_t)L_ * 64 * sizeof(float2));

  cvt_kernel<<<(int)(nBLE / 1024), 256, 0, stream>>>(x, xb, (int)nBLE);
  cvt_kernel<<<(int)((size_t)E_ * E_ / 1024), 256, 0, stream>>>(wq, wqb, E_ * E_);
  cvt_kernel<<<(int)((size_t)EKV_ * E_ / 1024), 256, 0, stream>>>(wk, wkb, EKV_ * E_);
  cvt_kernel<<<(int)((size_t)EKV_ * E_ / 1024), 256, 0, stream>>>(wv, wvb, EKV_ * E_);
  cvt_kernel<<<(int)((size_t)E_ * E_ / 1024), 256, 0, stream>>>(wo, wob, E_ * E_);
  trig_kernel<<<L_, 64, 0, stream>>>(offp, trig);

  const int M = B_ * L_;  // 4096
  gemm_nt<0><<<dim3(M / 128, E_ / 128), 256, 0, stream>>>(xb, wqb, bq, q_lin, M, E_, E_);
  gemm_nt<0><<<dim3(M / 128, EKV_ / 128), 256, 0, stream>>>(xb, wkb, bk, k_lin, M, EKV_, E_);
  gemm_nt<0><<<dim3(M / 128, EKV_ / 128), 256, 0, stream>>>(xb, wvb, bv, v_lin, M, EKV_, E_);
  rope_q_kernel<<<B_ * L_, 256, 0, stream>>>(q_lin, trig, qbuf);
  build_k_kernel<<<dim3(S_, B_ * HKV_), 128, 0, stream>>>(k_cache, k_lin, trig, k_all);
  build_vt_kernel<<<dim3(S_ / 64, D_ / 64, B_ * HKV_), 256, 0, stream>>>(v_cache, v_lin, vtall);
  attn_kernel<<<dim3(L_ / 128, B_ * H_), 256, 0, stream>>>(qbuf, k_all, vtall, attnout);
  gemm_nt<1><<<dim3(M / 128, E_ / 128), 256, 0, stream>>>(attnout, wob, nullptr, d_out, M, E_, E_);
}

// Round 6
// 365.907 us; speedup vs baseline: 3.0116x; 1.0781x over previous
//
#include <hip/hip_runtime.h>
#include <hip/hip_bf16.h>
#include <stdint.h>

typedef __bf16 bf16;
typedef __bf16 bf16x8 __attribute__((ext_vector_type(8)));
typedef __bf16 bf16x4 __attribute__((ext_vector_type(4)));
typedef float f32x4 __attribute__((ext_vector_type(4)));
typedef float f32x16 __attribute__((ext_vector_type(16)));

#define B_ 2
#define L_ 2048
#define E_ 2048
#define H_ 16
#define HKV_ 2
#define G_ 8
#define D_ 128
#define SPAST_ 2048
#define S_ 4096
#define EKV_ 256

#define MFMA16(a, b, c) __builtin_amdgcn_mfma_f32_16x16x32_bf16(a, b, c, 0, 0, 0)
#define MFMA32(a, b, c) __builtin_amdgcn_mfma_f32_32x32x16_bf16(a, b, c, 0, 0, 0)

__device__ __forceinline__ void gload16(const bf16* g, bf16* l) {
  __builtin_amdgcn_global_load_lds(
      (__attribute__((address_space(1))) void*)g,
      (__attribute__((address_space(3))) void*)l, 16, 0, 0);
}

// ---------------- f32 -> bf16 conversion ----------------
__global__ void cvt_kernel(const float* __restrict__ src, bf16* __restrict__ dst, int n) {
  int i = (blockIdx.x * 256 + threadIdx.x) * 4;
  if (i >= n) return;
  float4 v = *(const float4*)(src + i);
  bf16x4 o;
  o[0] = (bf16)v.x; o[1] = (bf16)v.y; o[2] = (bf16)v.z; o[3] = (bf16)v.w;
  *(bf16x4*)(dst + i) = o;
}

// ---------------- trig table ----------------
__global__ void trig_kernel(const int* __restrict__ offp, float2* __restrict__ trig) {
  int l = blockIdx.x, j = threadIdx.x;  // 64 threads
  float inv = exp2f(-(float)j * (13.287712379549449f / 64.0f));  // log2(10000)
  float ang = (float)(*offp + l) * inv;
  trig[l * 64 + j] = make_float2(cosf(ang), sinf(ang));
}

// ---------------- NT GEMM: C(M,N) = A(M,K) @ Bw(N,K)^T + bias ----------------
template <int OUTF32>
__global__ __launch_bounds__(256) void gemm_nt(const bf16* __restrict__ A,
                                               const bf16* __restrict__ Bw,
                                               const float* __restrict__ bias,
                                               void* __restrict__ Cout,
                                               int M, int N, int K) {
  __shared__ bf16 As[128 * 64];
  __shared__ bf16 Bs[128 * 64];
  const int tid = threadIdx.x;
  const int wid = tid >> 6, lane = tid & 63;
  const int ln15 = lane & 15, lq = lane >> 4;
  const int row0 = blockIdx.x * 128, col0 = blockIdx.y * 128;
  const int wr = wid >> 1, wc = wid & 1;
  f32x4 acc[4][4] = {};
  char* AsB = (char*)As;
  char* BsB = (char*)Bs;
  for (int k0 = 0; k0 < K; k0 += 64) {
#pragma unroll
    for (int j = 0; j < 4; j++) {
      int cid = j * 256 + tid;
      int r = cid >> 3, c = cid & 7;
      int csw = (c ^ (r & 7)) << 3;
      gload16(A + (size_t)(row0 + r) * K + k0 + csw, (bf16*)(AsB + (j * 256 + wid * 64) * 16));
      gload16(Bw + (size_t)(col0 + r) * K + k0 + csw, (bf16*)(BsB + (j * 256 + wid * 64) * 16));
    }
    __syncthreads();
    bf16x8 af[4][2], bfm[4][2];
#pragma unroll
    for (int m = 0; m < 4; m++) {
#pragma unroll
      for (int kk = 0; kk < 2; kk++) {
        int Ra = wr * 64 + m * 16 + ln15;
        int Rb = wc * 64 + m * 16 + ln15;
        int c = (kk << 2) + lq;
        af[m][kk] = *(const bf16x8*)(AsB + Ra * 128 + ((c ^ (Ra & 7)) << 4));
        bfm[m][kk] = *(const bf16x8*)(BsB + Rb * 128 + ((c ^ (Rb & 7)) << 4));
      }
    }
#pragma unroll
    for (int m = 0; m < 4; m++)
#pragma unroll
      for (int n = 0; n < 4; n++)
#pragma unroll
        for (int kk = 0; kk < 2; kk++)
          acc[m][n] = MFMA16(af[m][kk], bfm[n][kk], acc[m][n]);
    __syncthreads();
  }
#pragma unroll
  for (int m = 0; m < 4; m++) {
    int gr0 = row0 + wr * 64 + m * 16 + 4 * lq;
#pragma unroll
    for (int n = 0; n < 4; n++) {
      int gc = col0 + wc * 64 + n * 16 + ln15;
      float bv = bias ? bias[gc] : 0.0f;
#pragma unroll
      for (int reg = 0; reg < 4; reg++) {
        float v = acc[m][n][reg] + bv;
        size_t idx = (size_t)(gr0 + reg) * N + gc;
        if (OUTF32)
          ((float*)Cout)[idx] = v;
        else
          ((bf16*)Cout)[idx] = (bf16)v;
      }
    }
  }
}

// ---------------- RoPE on Q, scatter to (B,H,L,D), fold softmax scale*log2e ----------------
__global__ void rope_q_kernel(const bf16* __restrict__ q_lin, const float2* __restrict__ trig,
                              bf16* __restrict__ qbuf) {
  int bl = blockIdx.x;
  int b = bl >> 11, l = bl & 2047;  // L=2048
  const float QS = 0.08838834764831845f * 1.4426950408889634f;  // 1/sqrt(128) * log2(e)
  for (int i = threadIdx.x; i < H_ * 64; i += 256) {
    int h = i >> 6, j = i & 63;
    float2 cs = trig[l * 64 + j];
    float x1 = (float)q_lin[(size_t)bl * E_ + h * D_ + j];
    float x2 = (float)q_lin[(size_t)bl * E_ + h * D_ + 64 + j];
    size_t o = ((size_t)(b * H_ + h) * L_ + l) * D_ + j;
    qbuf[o] = (bf16)((x1 * cs.x - x2 * cs.y) * QS);
    qbuf[o + 64] = (bf16)((x2 * cs.x + x1 * cs.y) * QS);
  }
}

// ---------------- build k_all (B,HKV,S,D) ----------------
__global__ void build_k_kernel(const float* __restrict__ k_cache, const bf16* __restrict__ k_lin,
                               const float2* __restrict__ trig, bf16* __restrict__ k_all) {
  int d = threadIdx.x;  // 128
  int s = blockIdx.x;
  int bz = blockIdx.y;  // b*HKV + hkv
  size_t oidx = ((size_t)bz * S_ + s) * D_ + d;
  if (s < SPAST_) {
    k_all[oidx] = (bf16)k_cache[((size_t)bz * SPAST_ + s) * D_ + d];
  } else {
    int l = s - SPAST_;
    int b = bz >> 1, kh = bz & 1;
    int j = d & 63;
    float2 cs = trig[l * 64 + j];
    size_t base = (size_t)(b * L_ + l) * EKV_ + kh * D_;
    float x1 = (float)k_lin[base + j];
    float x2 = (float)k_lin[base + 64 + j];
    float v = (d < 64) ? (x1 * cs.x - x2 * cs.y) : (x2 * cs.x + x1 * cs.y);
    k_all[oidx] = (bf16)v;
  }
}

// ---------------- build transposed V: vtall (B,HKV,D,S) ----------------
__global__ void build_vt_kernel(const float* __restrict__ v_cache, const bf16* __restrict__ v_lin,
                                bf16* __restrict__ vtall) {
  __shared__ float tile[64][65];
  int s0 = blockIdx.x * 64;
  int d0 = blockIdx.y * 64;
  int bz = blockIdx.z;
  int b = bz >> 1, kh = bz & 1;
  for (int i = threadIdx.x; i < 4096; i += 256) {
    int ss = i >> 6, dd = i & 63;
    int s = s0 + ss;
    float v;
    if (s < SPAST_)
      v = v_cache[((size_t)bz * SPAST_ + s) * D_ + d0 + dd];
    else
      v = (float)v_lin[(size_t)(b * L_ + (s - SPAST_)) * EKV_ + kh * D_ + d0 + dd];
    tile[ss][dd] = v;
  }
  __syncthreads();
  for (int i = threadIdx.x; i < 4096; i += 256) {
    int dd = i >> 6, ss = i & 63;
    vtall[((size_t)bz * D_ + d0 + dd) * S_ + s0 + ss] = (bf16)tile[ss][dd];
  }
}

// ---------------- flash attention: 32x32 MFMA, in-register P, 2-phase staging ----------------
// grid (16, 32); 4 waves x 32 q-rows (one 32-wide tile each); 64-key chunks dbuf in LDS.
// Swapped QK^T (A=K,B=Q -> S^T): lanes l, l+32 share q=l&31 -> 1 shfl per reduce.
// P stays in registers: cvt_pk_bf16 + v_permlane32_swap build PV B-operands (T12).
// permlane32_swap semantics: VDST[i+32] <-> VSRC[i] (vdst HIGH <-> vsrc LOW). After
// swap(A,B): h=0 lanes hold (A_own, A_partner); h=1 lanes hold (B_partner, B_own).
// So swap(W0,W2)+swap(W1,W3) makes (W0',W1',W2',W3') the B-regs for the even 16-key step.
// 4-bit slot swizzle (c ^ (r&15)) on 256B LDS rows: conflict-free per 16-lane phase.
__global__ __launch_bounds__(256, 2) void attn_kernel(const bf16* __restrict__ qbuf,
                                                      const bf16* __restrict__ k_all,
                                                      const bf16* __restrict__ vtall,
                                                      bf16* __restrict__ attnout) {
  __shared__ bf16 Ks[2 * 64 * 128];   // [key][d], 256B rows, swizzled 16B slots
  __shared__ bf16 Vs[2 * 64 * 128];   // paired rows: row r = {d=2r | d=2r+1}, 256B
  const int tid = threadIdx.x;
  const int wid = tid >> 6, lane = tid & 63;
  const int l31 = lane & 31, h = lane >> 5;
  // balance remap: co-resident blocks (x,y) and (x,y+16) get q-blocks x and 15-x
  const int xq = ((blockIdx.y >> 4) & 1) ? (15 - (int)blockIdx.x) : (int)blockIdx.x;
  const int q0 = xq * 128;
  const int bh = blockIdx.y;
  const int b = bh / H_, hh = bh % H_;
  const int hkv = hh / G_;
  const bf16* kb = k_all + (size_t)(b * HKV_ + hkv) * S_ * D_;
  const bf16* vb = vtall + (size_t)(b * HKV_ + hkv) * D_ * S_;
  const int qw = q0 + wid * 32;  // wave's q base
  // Q fragments (B operand): col=q=l31, k = 8h+i; per kstep ks: d = ks*16+8h+i
  bf16x8 qf[8];
  {
    const bf16* qp = qbuf + ((size_t)(b * H_ + hh) * L_ + qw + l31) * D_ + h * 8;
#pragma unroll
    for (int ks = 0; ks < 8; ks++) qf[ks] = *(const bf16x8*)(qp + ks * 16);
  }
  f32x16 acc[4] = {};
  float mr = -3e38f, lr = 0.f;

  auto STAGE = [&](int buf, int s0) {
    char* kd = (char*)Ks + buf * 16384;
    char* vd = (char*)Vs + buf * 16384;
#pragma unroll
    for (int j = 0; j < 4; j++) {
      int cid = j * 256 + tid;
      int r = cid >> 4;
      int cl = (cid & 15) ^ (r & 15);  // logical slot stored at this linear pos
      // K: row r = key, slot cl -> d elems cl*8
      gload16(kb + (size_t)(s0 + r) * D_ + cl * 8, (bf16*)(kd + (j * 256 + wid * 64) * 16));
      // V: row r = d-pair; cl -> d = 2r + (cl>>3), keys (cl&7)*8
      gload16(vb + (size_t)(2 * r + (cl >> 3)) * S_ + s0 + (cl & 7) * 8,
              (bf16*)(vd + (j * 256 + wid * 64) * 16));
    }
  };

  const int nchunk = (q0 + 128 + SPAST_) >> 6;  // block-uniform
  const int smax_w = qw + 32 + SPAST_;

  STAGE(0, 0);
  __syncthreads();
  int cur = 0;
  for (int sc = 0; sc < nchunk; ++sc) {
    int s0 = sc << 6;
    if (sc + 1 < nchunk) STAGE(cur ^ 1, s0 + 64);  // prefetch next chunk
    if (s0 < smax_w) {
      char* kcur = (char*)Ks + cur * 16384;
      char* vcur = (char*)Vs + cur * 16384;
      // ---- swapped QK^T: st[t] = S^T tile; lane: q=l31, keys t*32+(r&3)+8*(r>>2)+4h
      f32x16 st[2];
      __builtin_amdgcn_s_setprio(1);
#pragma unroll
      for (int t = 0; t < 2; t++) {
        f32x16 a = {};
        int R = t * 32 + l31;
#pragma unroll
        for (int ks = 0; ks < 8; ks++) {
          int cl = 2 * ks + h;
          bf16x8 kf = *(const bf16x8*)(kcur + R * 256 + ((cl ^ (R & 15)) << 4));
          a = MFMA32(kf, qf[ks], a);
        }
        st[t] = a;
      }
      __builtin_amdgcn_s_setprio(0);
      // ---- causal mask (wave-uniform trigger: only diagonal chunks)
      if (s0 + 63 > qw + SPAST_) {
        int q = qw + l31;
#pragma unroll
        for (int t = 0; t < 2; t++)
#pragma unroll
          for (int r = 0; r < 16; r++) {
            int key = s0 + t * 32 + (r & 3) + 8 * (r >> 2) + 4 * h;
            if (key > q + SPAST_) st[t][r] = -1e30f;
          }
      }
      // ---- online softmax: in-lane tree + 1 shfl (partner holds other key-half)
      float mt = fmaxf(st[0][0], st[0][1]);
#pragma unroll
      for (int r = 2; r < 16; r++) mt = fmaxf(mt, st[0][r]);
#pragma unroll
      for (int r = 0; r < 16; r++) mt = fmaxf(mt, st[1][r]);
      mt = fmaxf(mt, __shfl_xor(mt, 32));
      // T13 defer-max: rescale only when tile max exceeds running max by >8
      if (__any(mt - mr > 8.0f)) {
        float mn = fmaxf(mr, mt);
        float fac = exp2f(mr - mn);
        mr = mn;
        lr *= fac;
#pragma unroll
        for (int dt = 0; dt < 4; dt++) acc[dt] *= fac;
      }
      float s = 0.f;
#pragma unroll
      for (int t = 0; t < 2; t++)
#pragma unroll
        for (int r = 0; r < 16; r++) {
          float p = exp2f(st[t][r] - mr);
          st[t][r] = p;
          s += p;
        }
      s += __shfl_xor(s, 32);
      lr += s;
      // ---- P -> bf16 pairs + permlane32_swap: build B-operand dwords in-register
      uint32_t W[2][8];
#pragma unroll
      for (int t = 0; t < 2; t++)
#pragma unroll
        for (int j = 0; j < 8; j++)
          asm("v_cvt_pk_bf16_f32 %0, %1, %2"
              : "=v"(W[t][j])
              : "v"(st[t][2 * j]), "v"(st[t][2 * j + 1]));
      // swap(vdst=W[s4+0], vsrc=W[s4+2]) etc. -- vdst.hi <-> vsrc.lo
#pragma unroll
      for (int t = 0; t < 2; t++)
#pragma unroll
        for (int s4 = 0; s4 < 8; s4 += 4) {
          asm volatile("v_permlane32_swap_b32 %0, %1" : "+v"(W[t][s4 + 0]), "+v"(W[t][s4 + 2]));
          asm volatile("v_permlane32_swap_b32 %0, %1" : "+v"(W[t][s4 + 1]), "+v"(W[t][s4 + 3]));
        }
      // ---- PV: O^T = V^T x P^T; A-frag from paired-row V LDS
      __builtin_amdgcn_s_setprio(1);
#pragma unroll
      for (int dt = 0; dt < 4; dt++) {
        int r = dt * 16 + (l31 >> 1);
        int clb = 8 * (l31 & 1) + h;
        f32x16 a = acc[dt];
#pragma unroll
        for (int ks = 0; ks < 4; ks++) {
          int cl = clb + 2 * ks;
          bf16x8 vf = *(const bf16x8*)(vcur + r * 256 + ((cl ^ (r & 15)) << 4));
          union { uint32_t u[4]; bf16x8 v; } pb;
          pb.u[0] = W[ks >> 1][(ks & 1) * 4 + 0];
          pb.u[1] = W[ks >> 1][(ks & 1) * 4 + 1];
          pb.u[2] = W[ks >> 1][(ks & 1) * 4 + 2];
          pb.u[3] = W[ks >> 1][(ks & 1) * 4 + 3];
          a = MFMA32(vf, pb.v, a);
        }
        acc[dt] = a;
      }
      __builtin_amdgcn_s_setprio(0);
    }
    __syncthreads();  // drains vmcnt (staging done) + wave sync
    cur ^= 1;
  }
  // ---- epilogue: lane holds O[q=l31][d = dt*32+8u+4h+e] -> 8B stores
  {
    float inv = 1.0f / lr;
    int q = qw + l31;
    size_t base = ((size_t)(b * L_ + q) * H_ + hh) * D_;
#pragma unroll
    for (int dt = 0; dt < 4; dt++)
#pragma unroll
      for (int u = 0; u < 4; u++) {
        bf16x4 o;
#pragma unroll
        for (int e = 0; e < 4; e++) o[e] = (bf16)(acc[dt][4 * u + e] * inv);
        *(bf16x4*)(attnout + base + dt * 32 + 8 * u + 4 * h) = o;
      }
  }
}

extern "C" void kernel_launch(void* const* d_in, const int* in_sizes, int n_in,
                              void* d_out, int out_size, void* d_ws, size_t ws_size,
                              hipStream_t stream) {
  const float* x = (const float*)d_in[0];
  const float* wq = (const float*)d_in[1];
  const float* wk = (const float*)d_in[2];
  const float* wv = (const float*)d_in[3];
  const float* wo = (const float*)d_in[4];
  const float* bq = (const float*)d_in[5];
  const float* bk = (const float*)d_in[6];
  const float* bv = (const float*)d_in[7];
  const float* k_cache = (const float*)d_in[8];
  const float* v_cache = (const float*)d_in[9];
  const int* offp = (const int*)d_in[10];

  char* w = (char*)d_ws;
  size_t off = 0;
  auto alloc = [&](size_t bytes) -> char* {
    char* p = w + off;
    off += (bytes + 255) & ~(size_t)255;
    return p;
  };
  const size_t nBLE = (size_t)B_ * L_ * E_;
  const size_t nBLKV = (size_t)B_ * L_ * EKV_;
  const size_t nKV = (size_t)B_ * HKV_ * S_ * D_;
  bf16* xb = (bf16*)alloc(nBLE * 2);
  bf16* wqb = (bf16*)alloc((size_t)E_ * E_ * 2);
  bf16* wkb = (bf16*)alloc((size_t)EKV_ * E_ * 2);
  bf16* wvb = (bf16*)alloc((size_t)EKV_ * E_ * 2);
  bf16* wob = (bf16*)alloc((size_t)E_ * E_ * 2);
  bf16* q_lin = (bf16*)alloc(nBLE * 2);
  bf16* k_lin = (bf16*)alloc(nBLKV * 2);
  bf16* v_lin = (bf16*)alloc(nBLKV * 2);
  bf16* qbuf = (bf16*)alloc(nBLE * 2);
  bf16* k_all = (bf16*)alloc(nKV * 2);
  bf16* vtall = (bf16*)alloc(nKV * 2);
  bf16* attnout = (bf16*)alloc(nBLE * 2);
  float2* trig = (float2*)alloc((size_t)L_ * 64 * sizeof(float2));

  cvt_kernel<<<(int)(nBLE / 1024), 256, 0, stream>>>(x, xb, (int)nBLE);
  cvt_kernel<<<(int)((size_t)E_ * E_ / 1024), 256, 0, stream>>>(wq, wqb, E_ * E_);
  cvt_kernel<<<(int)((size_t)EKV_ * E_ / 1024), 256, 0, stream>>>(wk, wkb, EKV_ * E_);
  cvt_kernel<<<(int)((size_t)EKV_ * E_ / 1024), 256, 0, stream>>>(wv, wvb, EKV_ * E_);
  cvt_kernel<<<(int)((size_t)E_ * E_ / 1024), 256, 0, stream>>>(wo, wob, E_ * E_);
  trig_kernel<<<L_, 64, 0, stream>>>(offp, trig);

  const int M = B_ * L_;  // 4096
  gemm_nt<0><<<dim3(M / 128, E_ / 128), 256, 0, stream>>>(xb, wqb, bq, q_lin, M, E_, E_);
  gemm_nt<0><<<dim3(M / 128, EKV_ / 128), 256, 0, stream>>>(xb, wkb, bk, k_lin, M, EKV_, E_);
  gemm_nt<0><<<dim3(M / 128, EKV_ / 128), 256, 0, stream>>>(xb, wvb, bv, v_lin, M, EKV_, E_);
  rope_q_kernel<<<B_ * L_, 256, 0, stream>>>(q_lin, trig, qbuf);
  build_k_kernel<<<dim3(S_, B_ * HKV_), 128, 0, stream>>>(k_cache, k_lin, trig, k_all);
  build_vt_kernel<<<dim3(S_ / 64, D_ / 64, B_ * HKV_), 256, 0, stream>>>(v_cache, v_lin, vtall);
  attn_kernel<<<dim3(L_ / 128, B_ * H_), 256, 0, stream>>>(qbuf, k_all, vtall, attnout);
  gemm_nt<1><<<dim3(M / 128, E_ / 128), 256, 0, stream>>>(attnout, wob, nullptr, d_out, M, E_, E_);
}